// Round 11
// baseline (186.509 us; speedup 1.0000x reference)
//
#include <hip/hip_runtime.h>

#define LAMC    10000.0f
#define INV_LAM 1e-4f
#define EPSC    1e-12f
#define TOLC    1e-6f
#define BLK     256

__device__ __forceinline__ float frcp(float x)  { return __builtin_amdgcn_rcpf(x); }
__device__ __forceinline__ float frsq(float x)  { return __builtin_amdgcn_rsqf(x); }
__device__ __forceinline__ float fsqrt_(float x){ return __builtin_amdgcn_sqrtf(x); }

// sign(phi(t)) without sqrt/div: phi = L - R*sqrt(q), q >= EPS > 0
__device__ __forceinline__ bool phi_pos(float t, float A, float p, float N, float b) {
    float q  = fmaxf(fmaf(t, fmaf(t, A, -2.0f * p), N), EPSC);
    float L  = fmaf(-t, A, p);        // p - t*A   (U_MAX = 1)
    float R  = fmaf(t, INV_LAM, b);   // b + t/LAM
    float L2 = L * L;
    float Rq = (R * R) * q;
    return (R < 0.0f) ? ((L >= 0.0f) || (L2 < Rq))
                      : ((L >  0.0f) && (L2 > Rq));
}

// branch-3 solve, proven tight bracket; 12 bisect + 5 safeguarded Newton.
// Numerics byte-identical to passing rounds 6/9.
__device__ __forceinline__ float2 heavy_solve(float ux, float uy,
                                              float ax, float ay, float b) {
    float A = fmaf(ax, ax, ay * ay);
    float p = fmaf(ax, ux, ay * uy);
    float N = fmaf(ux, ux, uy * uy);
    float t3;
    if (phi_pos(0.0f, A, p, N, b)) {
        float lo, hi;
        if (p > 0.0f) {
            float tA = p * frcp(fmaxf(A, 1e-30f));
            if (fmaf(tA, INV_LAM, b) >= 0.0f) { lo = 0.0f; hi = tA; }
            else                              { lo = tA;  hi = -LAMC * b; }
        } else {
            lo = 0.0f; hi = -LAMC * b;
        }
        #pragma unroll 1
        for (int k = 0; k < 12; ++k) {
            float mid = 0.5f * (lo + hi);
            bool pos = phi_pos(mid, A, p, N, b);
            lo = pos ? mid : lo;
            hi = pos ? hi : mid;
        }
        t3 = 0.5f * (lo + hi);
        #pragma unroll
        for (int k = 0; k < 5; ++k) {          // safeguarded Newton
            float q   = fmaxf(fmaf(t3, fmaf(t3, A, -2.0f * p), N), EPSC);
            float nrm = fsqrt_(q);
            float R   = fmaf(t3, INV_LAM, b);
            float f   = fmaf(-t3, A, p) - R * nrm;
            float df  = -A - nrm * INV_LAM - R * fmaf(t3, A, -p) * frcp(nrm);
            df = (fabsf(df) > 1e-8f) ? df : -1e-8f;
            bool fp = f > 0.0f;
            lo = fp ? t3 : lo;
            hi = fp ? hi : t3;
            t3 = fminf(fmaxf(t3 - f * frcp(df), lo), hi);
        }
    } else {
        // reference: bisection collapses to 0, then 3 unclamped Newton steps
        t3 = 0.0f;
        #pragma unroll
        for (int k = 0; k < 3; ++k) {
            float q   = fmaxf(fmaf(t3, fmaf(t3, A, -2.0f * p), N), EPSC);
            float nrm = fsqrt_(q);
            float R   = fmaf(t3, INV_LAM, b);
            float f   = fmaf(-t3, A, p) - R * nrm;
            float df  = -A - nrm * INV_LAM - R * fmaf(t3, A, -p) * frcp(nrm);
            df = (fabsf(df) > 1e-8f) ? df : -1e-8f;
            t3 = t3 - f * frcp(df);
        }
    }
    float q3  = fmaxf(fmaf(t3, fmaf(t3, A, -2.0f * p), N), EPSC);
    float k3  = fmaxf(fsqrt_(q3), 1.0f);
    float inv = frcp(k3);
    return make_float2(fmaf(-t3, ax, ux) * inv, fmaf(-t3, ay, uy) * inv);
}

// easy paths; returns true if heavy (branch 3). Exports (ax,ay,b).
__device__ __forceinline__ bool easy_row(float ux, float uy,
                                         float px, float py, float vx, float vy,
                                         float& ox, float& oy,
                                         float& axo, float& ayo, float& bo) {
    float ax = -2.0f * px, ay = -2.0f * py;
    float h  = fmaf(px, px, py * py) - 1.0f;
    float b  = fmaf(2.0f, h, -2.0f * fmaf(px, vx, py * vy));
    axo = ax; ayo = ay; bo = b;
    float A  = fmaf(ax, ax, ay * ay);
    float p  = fmaf(ax, ux, ay * uy);
    float N  = fmaf(ux, ux, uy * uy);
    float s1 = fminf(1.0f, frsq(fmaxf(N, EPSC)));   // min(1, 1/|u|)
    float u1x = ux * s1, u1y = uy * s1;
    ox = u1x; oy = u1y;
    if (fmaf(ax, u1x, ay * u1y) <= b + TOLC) return false;
    float t2  = LAMC * (p - b) * frcp(fmaf(LAMC, A, 1.0f));
    float u2x = fmaf(-t2, ax, ux), u2y = fmaf(-t2, ay, uy);
    if (t2 >= -TOLC && fmaf(u2x, u2x, u2y * u2y) <= 1.0f + TOLC) {
        ox = u2x; oy = u2y; return false;
    }
    return true;
}

// R9's inline solver structure, but obs is staged into LDS with three
// perfectly DENSE float4 loads per thread (the strided direct loads were
// inflating per-CU cache-line requests ~2-3x — the actual plateau).
__global__ __launch_bounds__(BLK) void cbf_kernel(const float4* __restrict__ u4,
                                                  const float4* __restrict__ obs4,
                                                  float4* __restrict__ out4,
                                                  int npair) {
    __shared__ float4 sobs[3 * BLK];    // 512 rows * 6 floats = 768 float4
    int tid = threadIdx.x;
    int i   = blockIdx.x * BLK + tid;
    bool valid = i < npair;

    size_t cb = (size_t)blockIdx.x * (3 * BLK);       // first obs chunk of block
    size_t totch = (size_t)npair * 3;                 // total obs float4 chunks
    float4 z = make_float4(0.f, 0.f, 0.f, 0.f);
    sobs[tid]           = (cb + tid           < totch) ? obs4[cb + tid]           : z;
    sobs[tid + BLK]     = (cb + tid + BLK     < totch) ? obs4[cb + tid + BLK]     : z;
    sobs[tid + 2 * BLK] = (cb + tid + 2 * BLK < totch) ? obs4[cb + tid + 2 * BLK] : z;
    float4 u = valid ? u4[i] : z;
    __syncthreads();

    const float* s = (const float*)sobs;
    // local row pair: rows 2*tid, 2*tid+1 ; row r fields at floats 6r+2..5
    int f0 = 12 * tid;                  // float base of row 2*tid
    float2 p0 = *(const float2*)(s + f0 + 2);
    float2 v0 = *(const float2*)(s + f0 + 4);
    float2 p1 = *(const float2*)(s + f0 + 8);
    float2 v1 = *(const float2*)(s + f0 + 10);

    float4 r;
    float ax0, ay0, bb0, ax1, ay1, bb1;
    bool h0 = easy_row(u.x, u.y, p0.x, p0.y, v0.x, v0.y, r.x, r.y, ax0, ay0, bb0);
    bool h1 = easy_row(u.z, u.w, p1.x, p1.y, v1.x, v1.y, r.z, r.w, ax1, ay1, bb1);
    if (h0) { float2 t = heavy_solve(u.x, u.y, ax0, ay0, bb0); r.x = t.x; r.y = t.y; }
    if (h1) { float2 t = heavy_solve(u.z, u.w, ax1, ay1, bb1); r.z = t.x; r.w = t.y; }
    if (valid) out4[i] = r;
}

extern "C" void kernel_launch(void* const* d_in, const int* in_sizes, int n_in,
                              void* d_out, int out_size, void* d_ws, size_t ws_size,
                              hipStream_t stream) {
    const float* u_nom = (const float*)d_in[0];
    const float* obs   = (const float*)d_in[1];
    float* out = (float*)d_out;
    int rows   = in_sizes[0] / 2;     // B
    int npair  = rows / 2;            // 2 rows per thread
    int blocks = (npair + BLK - 1) / BLK;
    cbf_kernel<<<blocks, BLK, 0, stream>>>((const float4*)u_nom,
                                           (const float4*)obs,
                                           (float4*)out, npair);
}